// Round 12
// baseline (545.182 us; speedup 1.0000x reference)
//
#include <hip/hip_runtime.h>

// Problem constants
constexpr int Nn  = 50000;
constexpr int Ne  = 200000;
constexpr int Bg  = 64;
constexpr int DN  = 128;
constexpr int DE  = 64;
constexpr int HD  = 64;
constexpr int INN = 64;
constexpr int INE = 16;
constexpr int LAY = 6;
constexpr int SB  = 196;  // scan blocks: 196*256 >= Nn

typedef __attribute__((ext_vector_type(8))) short sh8;  // 8 bf16 = 4 VGPR
typedef __attribute__((ext_vector_type(4))) float f4;   // C/D frag

__device__ inline unsigned short f2bf(float x) {
  union { float f; unsigned u; } v; v.f = x;
  unsigned r = v.u + 0x7FFF + ((v.u >> 16) & 1);  // RNE
  return (unsigned short)(r >> 16);
}
__device__ inline float bf2f(unsigned short u) {
  union { unsigned u; float f; } v; v.u = ((unsigned)u) << 16; return v.f;
}
__device__ inline f4 mfma16(sh8 a, sh8 b, f4 c) {
  return __builtin_amdgcn_mfma_f32_16x16x32_bf16(a, b, c, 0, 0, 0);
}

// ---------------------------------------------------------------------------
// CSR build: histogram -> exclusive scan -> scatter (dst-sorted permutation)
// ---------------------------------------------------------------------------
__global__ void hist(const int* __restrict__ dst, int* __restrict__ deg) {
  const int j = blockIdx.x * blockDim.x + threadIdx.x;
  if (j < Ne) atomicAdd(&deg[dst[j]], 1);
}

__global__ __launch_bounds__(256) void scan1(const int* __restrict__ deg,
                                             int* __restrict__ rp,
                                             int* __restrict__ bsum) {
  __shared__ int s[256];
  const int t = threadIdx.x, i = blockIdx.x * 256 + t;
  const int v = (i < Nn) ? deg[i] : 0;
  s[t] = v; __syncthreads();
  for (int off = 1; off < 256; off <<= 1) {
    const int x = (t >= off) ? s[t - off] : 0;
    __syncthreads();
    s[t] += x;
    __syncthreads();
  }
  if (i < Nn) rp[i] = s[t] - v;  // intra-block exclusive
  if (t == 255) bsum[blockIdx.x] = s[255];
}

__global__ __launch_bounds__(256) void scan2(const int* __restrict__ bsum,
                                             int* __restrict__ boff) {
  __shared__ int s[256];
  const int t = threadIdx.x;
  const int v = (t < SB) ? bsum[t] : 0;
  s[t] = v; __syncthreads();
  for (int off = 1; off < 256; off <<= 1) {
    const int x = (t >= off) ? s[t - off] : 0;
    __syncthreads();
    s[t] += x;
    __syncthreads();
  }
  if (t < SB) boff[t] = s[t] - v;
}

__global__ __launch_bounds__(256) void scan3(int* __restrict__ rp,
                                             const int* __restrict__ boff,
                                             const int* __restrict__ deg,
                                             int* __restrict__ cursor,
                                             float* __restrict__ invdeg) {
  const int i = blockIdx.x * 256 + threadIdx.x;
  if (i < Nn) {
    const int r = rp[i] + boff[i >> 8];
    rp[i] = r;
    cursor[i] = r;
    invdeg[i] = 1.0f / fmaxf((float)deg[i], 1.0f);
  }
  if (i == 0) rp[Nn] = Ne;
}

__global__ void scatter(const int* __restrict__ src, const int* __restrict__ dst,
                        int* __restrict__ cursor, int* __restrict__ pos,
                        int* __restrict__ src_s, int* __restrict__ dst_s) {
  const int j = blockIdx.x * blockDim.x + threadIdx.x;
  if (j < Ne) {
    const int d = dst[j];
    const int p = atomicAdd(&cursor[d], 1);
    pos[j] = p;       // dst-sorted position of original edge j
    src_s[p] = src[j];
    dst_s[p] = d;
  }
}

// ---------------------------------------------------------------------------
// Weight prep.
// wpT[l][n][k] n<64: fused (W1s + mw@W1e) col n; n>=64: W1d col (n-64). K=128.
// w1eT[l][n][k] = W1e[k][n]; ew2T[l][n][k] = W2[k][n].
// ---------------------------------------------------------------------------
__global__ __launch_bounds__(64) void prep_we(const float* __restrict__ ew1,
                                              const float* __restrict__ mw,
                                              const float* __restrict__ ew2,
                                              unsigned short* __restrict__ wpT,
                                              unsigned short* __restrict__ w1eT,
                                              unsigned short* __restrict__ ew2T) {
  const int l = blockIdx.x >> 6, n = blockIdx.x & 63, t = threadIdx.x;
  const float* E1 = ew1 + (long)l * 320 * 64;
  const float* MW = mw + (long)l * 128 * 64;
  const float* E2 = ew2 + (long)l * 64 * 64;
  unsigned short* WP = wpT + (long)l * 128 * 128;
  __shared__ float c[64];
  c[t] = E1[(256 + t) * 64 + n];  // W1e column n
  __syncthreads();
  for (int k = t; k < 128; k += 64) {
    float s = E1[k * 64 + n];
    for (int j = 0; j < 64; ++j) s += MW[k * 64 + j] * c[j];
    WP[n * 128 + k] = f2bf(s);                        // Ps weight col n
    WP[(64 + n) * 128 + k] = f2bf(E1[(128 + k) * 64 + n]);  // Pd weight col n
  }
  w1eT[(long)l * 64 * 64 + n * 64 + t] = f2bf(E1[(256 + t) * 64 + n]);
  ew2T[(long)l * 64 * 64 + n * 64 + t] = f2bf(E2[t * 64 + n]);
}

__global__ __launch_bounds__(64) void prep_wv(const float* __restrict__ vw1,
                                              const float* __restrict__ vw2,
                                              unsigned short* __restrict__ vw1T,
                                              unsigned short* __restrict__ vw2T) {
  const int l = blockIdx.x >> 7, n = blockIdx.x & 127, t = threadIdx.x;
  vw2T[(long)l * 128 * 64 + n * 64 + t] = f2bf(vw2[(long)l * 64 * 128 + t * 128 + n]);
  if (n < 64) {
    for (int k = t; k < 192; k += 64)
      vw1T[(long)l * 64 * 192 + n * 192 + k] = f2bf(vw1[(long)l * 192 * 64 + k * 64 + n]);
  }
}

// wxT[n][k]: lin_x_w [64][128] -> transposed bf16 [128][64]
__global__ __launch_bounds__(64) void prep_wx(const float* __restrict__ w,
                                              unsigned short* __restrict__ wxT) {
  const int n = blockIdx.x, t = threadIdx.x;
  wxT[n * INN + t] = f2bf(w[t * DN + n]);
}

// ---------------------------------------------------------------------------
// Node encoder (MFMA): h = x @ lin_x_w + b. Wave = 32 nodes, K=64, N=128.
// ---------------------------------------------------------------------------
__global__ __launch_bounds__(256) void enc_node_mfma(
    const float* __restrict__ x,
    const unsigned short* __restrict__ wxT,  // [128][64]
    const float* __restrict__ b,
    unsigned short* __restrict__ hb) {
  const int lane = threadIdx.x & 63;
  const int wv   = threadIdx.x >> 6;
  const int quad = lane >> 4;
  const int lm   = lane & 15;
  const int wid  = blockIdx.x * 4 + wv;
  const int ntiles = (Nn + 31) / 32;  // 1563
  if (wid >= ntiles) return;
  const int i0 = wid * 32;

  bool mv[2];
#pragma unroll
  for (int mt = 0; mt < 2; ++mt) mv[mt] = (i0 + mt * 16) < Nn;

  f4 acc[2][8];
#pragma unroll
  for (int mt = 0; mt < 2; ++mt)
#pragma unroll
    for (int nt = 0; nt < 8; ++nt) acc[mt][nt] = f4{0.f, 0.f, 0.f, 0.f};

#pragma unroll
  for (int ks = 0; ks < 2; ++ks) {
    const int kb = ks * 32 + quad * 8;
    sh8 a[2], bfr[8];
#pragma unroll
    for (int mt = 0; mt < 2; ++mt) {
      const int row = i0 + mt * 16 + lm;
      if (mv[mt] && row < Nn) {
        const float* xp = x + (long)row * INN + kb;
        const float4 v0 = *(const float4*)xp;
        const float4 v1 = *(const float4*)(xp + 4);
        a[mt][0] = (short)f2bf(v0.x); a[mt][1] = (short)f2bf(v0.y);
        a[mt][2] = (short)f2bf(v0.z); a[mt][3] = (short)f2bf(v0.w);
        a[mt][4] = (short)f2bf(v1.x); a[mt][5] = (short)f2bf(v1.y);
        a[mt][6] = (short)f2bf(v1.z); a[mt][7] = (short)f2bf(v1.w);
      } else a[mt] = (sh8)0;
    }
#pragma unroll
    for (int nt = 0; nt < 8; ++nt)
      bfr[nt] = *(const sh8*)(wxT + (nt * 16 + lm) * INN + kb);
#pragma unroll
    for (int mt = 0; mt < 2; ++mt)
#pragma unroll
      for (int nt = 0; nt < 8; ++nt)
        acc[mt][nt] = mfma16(a[mt], bfr[nt], acc[mt][nt]);
  }
  float bv[8];
#pragma unroll
  for (int nt = 0; nt < 8; ++nt) bv[nt] = b[nt * 16 + lm];
#pragma unroll
  for (int mt = 0; mt < 2; ++mt) {
    if (!mv[mt]) continue;
#pragma unroll
    for (int r = 0; r < 4; ++r) {
      const int row = i0 + mt * 16 + quad * 4 + r;
      if (row >= Nn) continue;
#pragma unroll
      for (int nt = 0; nt < 8; ++nt)
        hb[(long)row * DN + nt * 16 + lm] = f2bf(acc[mt][nt][r] + bv[nt]);
    }
  }
}

// ---------------------------------------------------------------------------
// Edge encoder: sequential coalesced read of ea, scatter-write to dst-sorted eb.
// ---------------------------------------------------------------------------
__global__ __launch_bounds__(256) void enc_edge(const float* __restrict__ ea,
                                                const int* __restrict__ pos,
                                                const float* __restrict__ w,
                                                const float* __restrict__ b,
                                                unsigned short* __restrict__ eb) {
  __shared__ float S[64 * INE];
  const int t = threadIdx.x;
  const int j0 = blockIdx.x * 64;  // Ne/64 = 3125 blocks
  *(float4*)&S[t * 4] = *(const float4*)&ea[(long)j0 * INE + t * 4];
  __syncthreads();
  const int lane = t & 63, wv = t >> 6;
  float wreg[INE];
#pragma unroll
  for (int k = 0; k < INE; ++k) wreg[k] = w[k * DE + lane];
  const float bias = b[lane];
#pragma unroll
  for (int el = 0; el < 16; ++el) {
    const int e = wv * 16 + el;
    float acc = bias;
#pragma unroll
    for (int k = 0; k < INE; ++k) acc += S[e * INE + k] * wreg[k];
    eb[(long)pos[j0 + e] * DE + lane] = f2bf(acc);
  }
}

// ---------------------------------------------------------------------------
// Per-node projection: P = hb @ [W1s' | W1d]  (Nn x 128, bf16).
// Wave = 32 rows, K=128, N=128. Streaming; staged coalesced stores.
// ---------------------------------------------------------------------------
constexpr int PP = 136;  // P-staging pitch (272B rows)

__global__ __launch_bounds__(256) void proj_mfma(
    const unsigned short* __restrict__ hb,
    const unsigned short* __restrict__ wpT,  // [128][128]
    unsigned short* __restrict__ P) {
  __shared__ unsigned short Us[4][32 * PP];
  const int lane = threadIdx.x & 63;
  const int wv   = threadIdx.x >> 6;
  const int quad = lane >> 4;
  const int lm   = lane & 15;
  const int kq   = quad * 8;
  const int wid  = blockIdx.x * 4 + wv;
  const int ntiles = (Nn + 31) / 32;  // 1563
  if (wid >= ntiles) return;
  const int i0 = wid * 32;
  unsigned short* us = Us[wv];

  bool mv[2];
#pragma unroll
  for (int mt = 0; mt < 2; ++mt) mv[mt] = (i0 + mt * 16) < Nn;

  sh8 a[2][4];
#pragma unroll
  for (int mt = 0; mt < 2; ++mt) {
    const int row = i0 + mt * 16 + lm;
    if (mv[mt]) {
#pragma unroll
      for (int ks = 0; ks < 4; ++ks)
        a[mt][ks] = *(const sh8*)(hb + (long)row * DN + ks * 32 + kq);
    } else {
#pragma unroll
      for (int ks = 0; ks < 4; ++ks) a[mt][ks] = (sh8)0;
    }
  }

  f4 acc[2][8];
#pragma unroll
  for (int mt = 0; mt < 2; ++mt)
#pragma unroll
    for (int nt = 0; nt < 8; ++nt) acc[mt][nt] = f4{0.f, 0.f, 0.f, 0.f};

#pragma unroll
  for (int ks = 0; ks < 4; ++ks) {
    const int kb = ks * 32 + kq;
    sh8 bfr[8];
#pragma unroll
    for (int nt = 0; nt < 8; ++nt)
      bfr[nt] = *(const sh8*)(wpT + (nt * 16 + lm) * 128 + kb);
#pragma unroll
    for (int mt = 0; mt < 2; ++mt)
#pragma unroll
      for (int nt = 0; nt < 8; ++nt)
        acc[mt][nt] = mfma16(a[mt][ks], bfr[nt], acc[mt][nt]);
  }

#pragma unroll
  for (int mt = 0; mt < 2; ++mt)
#pragma unroll
    for (int nt = 0; nt < 8; ++nt)
#pragma unroll
      for (int r = 0; r < 4; ++r)
        us[(mt * 16 + quad * 4 + r) * PP + nt * 16 + lm] = f2bf(acc[mt][nt][r]);
#pragma unroll
  for (int s = 0; s < 8; ++s) {
    const int row = s * 4 + (lane >> 4);
    const int col8 = (lane & 15) * 8;
    if (i0 + row < Nn) {
      const sh8 v = *(const sh8*)&us[row * PP + col8];
      *(sh8*)(P + (long)(i0 + row) * 128 + col8) = v;
    }
  }
}

// ---------------------------------------------------------------------------
// Edge layer (MFMA). u = relu(Ps[src] + Pd[dst] + e@W1e + b1) via identity
// MFMAs; e' = [u|e]@[W2;I] + b2. Weights in LDS; grid-stride; staged stores.
// ---------------------------------------------------------------------------
constexpr int UP = 72;   // Us / weight LDS pitch (144B rows)

__global__ __launch_bounds__(256) void edge_layer_mfma(
    const unsigned short* __restrict__ P,
    unsigned short* __restrict__ eb,
    const int* __restrict__ src_s, const int* __restrict__ dst_s,
    const unsigned short* __restrict__ w1eT,  // [64][64]
    const unsigned short* __restrict__ ew2T,  // [64][64]
    const float* __restrict__ b1, const float* __restrict__ b2) {
  __shared__ unsigned short W1l[64 * UP];   // 9216 B
  __shared__ unsigned short W2l[64 * UP];   // 9216 B
  __shared__ unsigned short Us[4][32 * UP]; // 18432 B (total 36864 B -> 4 blocks/CU)
  const int t    = threadIdx.x;
  const int lane = t & 63;
  const int wv   = t >> 6;
  const int quad = lane >> 4;
  const int lm   = lane & 15;
  const int kq   = quad * 8;
  unsigned short* us = Us[wv];

#pragma unroll
  for (int c = 0; c < 2; ++c) {
    const int cc = c * 256 + t;
    const int n = cc >> 3, kc = (cc & 7) * 8;
    *(sh8*)&W1l[n * UP + kc] = *(const sh8*)(w1eT + n * 64 + kc);
    *(sh8*)&W2l[n * UP + kc] = *(const sh8*)(ew2T + n * 64 + kc);
  }
  __syncthreads();

  float b1v[4], b2v[4];
  sh8 bi[4];
#pragma unroll
  for (int nt = 0; nt < 4; ++nt) {
    b1v[nt] = b1[nt * 16 + lm];
    b2v[nt] = b2[nt * 16 + lm];
    const int d = nt * 16 + lm - (nt >> 1) * 32 - kq;
#pragma unroll
    for (int jj = 0; jj < 8; ++jj) bi[nt][jj] = (d == jj) ? (short)0x3F80 : (short)0;
  }

  const int ntiles = Ne / 32;  // 6250
  const int nw = gridDim.x * 4;
  for (int wid = blockIdx.x * 4 + wv; wid < ntiles; wid += nw) {
    const int j0 = wid * 32;

    sh8 as_[2][2], ad_[2][2], ae_[2][2];
#pragma unroll
    for (int mt = 0; mt < 2; ++mt) {
      const int j = j0 + mt * 16 + lm;
      const long srow = (long)src_s[j] * 128;
      const long drow = (long)dst_s[j] * 128 + 64;
#pragma unroll
      for (int ks = 0; ks < 2; ++ks) {
        as_[mt][ks] = *(const sh8*)(P + srow + ks * 32 + kq);
        ad_[mt][ks] = *(const sh8*)(P + drow + ks * 32 + kq);
        ae_[mt][ks] = *(const sh8*)(eb + (long)j * DE + ks * 32 + kq);
      }
    }

    f4 acc[2][4];
#pragma unroll
    for (int mt = 0; mt < 2; ++mt)
#pragma unroll
      for (int nt = 0; nt < 4; ++nt) acc[mt][nt] = f4{0.f, 0.f, 0.f, 0.f};
#pragma unroll
    for (int ks = 0; ks < 2; ++ks) {
      const int kb = ks * 32 + kq;
      sh8 b[4];
#pragma unroll
      for (int nt = 0; nt < 4; ++nt)
        b[nt] = *(const sh8*)&W1l[(nt * 16 + lm) * UP + kb];
#pragma unroll
      for (int mt = 0; mt < 2; ++mt)
#pragma unroll
        for (int nt = 0; nt < 4; ++nt)
          acc[mt][nt] = mfma16(ae_[mt][ks], b[nt], acc[mt][nt]);
    }
#pragma unroll
    for (int nt = 0; nt < 4; ++nt)
#pragma unroll
      for (int mt = 0; mt < 2; ++mt) {
        acc[mt][nt] = mfma16(as_[mt][nt >> 1], bi[nt], acc[mt][nt]);
        acc[mt][nt] = mfma16(ad_[mt][nt >> 1], bi[nt], acc[mt][nt]);
      }

#pragma unroll
    for (int mt = 0; mt < 2; ++mt)
#pragma unroll
      for (int nt = 0; nt < 4; ++nt)
#pragma unroll
        for (int r = 0; r < 4; ++r) {
          const int row = mt * 16 + quad * 4 + r;
          const int col = nt * 16 + lm;
          us[row * UP + col] = f2bf(fmaxf(acc[mt][nt][r] + b1v[nt], 0.f));
        }

    f4 acc2[2][4];
#pragma unroll
    for (int mt = 0; mt < 2; ++mt)
#pragma unroll
      for (int nt = 0; nt < 4; ++nt) acc2[mt][nt] = f4{0.f, 0.f, 0.f, 0.f};
#pragma unroll
    for (int ks = 0; ks < 2; ++ks) {
      const int kb = ks * 32 + kq;
      sh8 au[2], b[4];
#pragma unroll
      for (int mt = 0; mt < 2; ++mt)
        au[mt] = *(const sh8*)&us[(mt * 16 + lm) * UP + kb];
#pragma unroll
      for (int nt = 0; nt < 4; ++nt)
        b[nt] = *(const sh8*)&W2l[(nt * 16 + lm) * UP + kb];
#pragma unroll
      for (int mt = 0; mt < 2; ++mt)
#pragma unroll
        for (int nt = 0; nt < 4; ++nt)
          acc2[mt][nt] = mfma16(au[mt], b[nt], acc2[mt][nt]);
    }
#pragma unroll
    for (int nt = 0; nt < 4; ++nt)
#pragma unroll
      for (int mt = 0; mt < 2; ++mt)
        acc2[mt][nt] = mfma16(ae_[mt][nt >> 1], bi[nt], acc2[mt][nt]);

#pragma unroll
    for (int mt = 0; mt < 2; ++mt)
#pragma unroll
      for (int nt = 0; nt < 4; ++nt)
#pragma unroll
        for (int r = 0; r < 4; ++r)
          us[(mt * 16 + quad * 4 + r) * UP + nt * 16 + lm] =
              f2bf(acc2[mt][nt][r] + b2v[nt]);
#pragma unroll
    for (int s = 0; s < 4; ++s) {
      const int row = s * 8 + (lane >> 3);
      const sh8 v = *(const sh8*)&us[row * UP + (lane & 7) * 8];
      *(sh8*)(eb + (long)(j0 + row) * DE + (lane & 7) * 8) = v;
    }
  }
}

// ---------------------------------------------------------------------------
// Node layer (MFMA) with FUSED csr-mean (R9/R10 version).
// ---------------------------------------------------------------------------
constexpr int VP1 = 200;              // vw1T LDS pitch (400B rows)
constexpr int VP2 = 72;               // vw2T LDS pitch (144B rows)
constexpr int V2OFF = 64 * VP1;       // vw2T offset in Wl

__global__ __launch_bounds__(256) void node_layer_mfma(
    unsigned short* __restrict__ hb,
    const unsigned short* __restrict__ eb,
    const int* __restrict__ rp,
    const float* __restrict__ invdeg,
    const unsigned short* __restrict__ vw1T,  // [64][192]
    const unsigned short* __restrict__ vw2T,  // [128][64]
    const float* __restrict__ b1, const float* __restrict__ b2) {
  __shared__ unsigned short Wl[64 * VP1 + 128 * VP2];  // 44032 B
  __shared__ unsigned short Us[4][32 * UP];            // 18432 B (total 62464 B)
  const int t    = threadIdx.x;
  const int lane = t & 63;
  const int wv   = t >> 6;
  const int quad = lane >> 4;
  const int lm   = lane & 15;
  const int kq   = quad * 8;
  unsigned short* us = Us[wv];

#pragma unroll
  for (int c = 0; c < 6; ++c) {
    const int cc = c * 256 + t;
    const int n = cc / 24, kc = (cc % 24) * 8;
    *(sh8*)&Wl[n * VP1 + kc] = *(const sh8*)(vw1T + n * 192 + kc);
  }
#pragma unroll
  for (int c = 0; c < 4; ++c) {
    const int cc = c * 256 + t;
    const int n = cc / 8, kc = (cc % 8) * 8;
    *(sh8*)&Wl[V2OFF + n * VP2 + kc] = *(const sh8*)(vw2T + n * 64 + kc);
  }
  __syncthreads();

  float b1v[4];
  sh8 bi[4];
#pragma unroll
  for (int nt = 0; nt < 4; ++nt) {
    b1v[nt] = b1[nt * 16 + lm];
    const int d = nt * 16 + lm - (nt >> 1) * 32 - kq;
#pragma unroll
    for (int jj = 0; jj < 8; ++jj) bi[nt][jj] = (d == jj) ? (short)0x3F80 : (short)0;
  }
  float b2v[2][4];
#pragma unroll
  for (int nh = 0; nh < 2; ++nh)
#pragma unroll
    for (int nt = 0; nt < 4; ++nt) b2v[nh][nt] = b2[nh * 64 + nt * 16 + lm];

  const int ntiles = (Nn + 31) / 32;  // 1563
  const int nw = gridDim.x * 4;
  for (int wid = blockIdx.x * 4 + wv; wid < ntiles; wid += nw) {
    const int i0 = wid * 32;
    bool mv[2];
#pragma unroll
    for (int mt = 0; mt < 2; ++mt) mv[mt] = (i0 + mt * 16) < Nn;

    sh8 a[2][6];
#pragma unroll
    for (int mt = 0; mt < 2; ++mt) {
      const int row = i0 + mt * 16 + lm;
      if (mv[mt]) {
#pragma unroll
        for (int ks = 0; ks < 4; ++ks)
          a[mt][ks] = *(const sh8*)(hb + (long)row * DN + ks * 32 + kq);
        const int js = rp[row], je = rp[row + 1];
        float m0[8], m1[8];
#pragma unroll
        for (int c = 0; c < 8; ++c) { m0[c] = 0.f; m1[c] = 0.f; }
        for (int j = js; j < je; ++j) {
          const sh8 v0 = *(const sh8*)(eb + (long)j * DE + kq);
          const sh8 v1 = *(const sh8*)(eb + (long)j * DE + 32 + kq);
#pragma unroll
          for (int c = 0; c < 8; ++c) {
            m0[c] += bf2f((unsigned short)v0[c]);
            m1[c] += bf2f((unsigned short)v1[c]);
          }
        }
        const float inv = invdeg[row];
        sh8 f0, f1;
#pragma unroll
        for (int c = 0; c < 8; ++c) {
          f0[c] = (short)f2bf(m0[c] * inv);
          f1[c] = (short)f2bf(m1[c] * inv);
        }
        a[mt][4] = f0;
        a[mt][5] = f1;
      } else {
#pragma unroll
        for (int ks = 0; ks < 6; ++ks) a[mt][ks] = (sh8)0;
      }
    }

    f4 acc[2][4];
#pragma unroll
    for (int mt = 0; mt < 2; ++mt)
#pragma unroll
      for (int nt = 0; nt < 4; ++nt) acc[mt][nt] = f4{0.f, 0.f, 0.f, 0.f};
#pragma unroll
    for (int ks = 0; ks < 6; ++ks) {
      const int kb = ks * 32 + kq;
      sh8 b[4];
#pragma unroll
      for (int nt = 0; nt < 4; ++nt)
        b[nt] = *(const sh8*)&Wl[(nt * 16 + lm) * VP1 + kb];
#pragma unroll
      for (int mt = 0; mt < 2; ++mt)
#pragma unroll
        for (int nt = 0; nt < 4; ++nt)
          acc[mt][nt] = mfma16(a[mt][ks], b[nt], acc[mt][nt]);
    }
#pragma unroll
    for (int mt = 0; mt < 2; ++mt)
#pragma unroll
      for (int nt = 0; nt < 4; ++nt)
#pragma unroll
        for (int r = 0; r < 4; ++r) {
          const int row = mt * 16 + quad * 4 + r;
          const int col = nt * 16 + lm;
          us[row * UP + col] = f2bf(fmaxf(acc[mt][nt][r] + b1v[nt], 0.f));
        }

    sh8 au[2][2];
#pragma unroll
    for (int ks = 0; ks < 2; ++ks)
#pragma unroll
      for (int mt = 0; mt < 2; ++mt)
        au[mt][ks] = *(const sh8*)&us[(mt * 16 + lm) * UP + ks * 32 + kq];

#pragma unroll
    for (int nh = 0; nh < 2; ++nh) {
      f4 acc2[2][4];
#pragma unroll
      for (int mt = 0; mt < 2; ++mt)
#pragma unroll
        for (int nt = 0; nt < 4; ++nt) acc2[mt][nt] = f4{0.f, 0.f, 0.f, 0.f};
#pragma unroll
      for (int ks = 0; ks < 2; ++ks) {
        const int kb = ks * 32 + kq;
        sh8 b[4];
#pragma unroll
        for (int nt = 0; nt < 4; ++nt)
          b[nt] = *(const sh8*)&Wl[V2OFF + (nh * 64 + nt * 16 + lm) * VP2 + kb];
#pragma unroll
        for (int mt = 0; mt < 2; ++mt)
#pragma unroll
          for (int nt = 0; nt < 4; ++nt)
            acc2[mt][nt] = mfma16(au[mt][ks], b[nt], acc2[mt][nt]);
      }
#pragma unroll
      for (int nt = 0; nt < 4; ++nt)
#pragma unroll
        for (int mt = 0; mt < 2; ++mt)
          acc2[mt][nt] = mfma16(a[mt][nh * 2 + (nt >> 1)], bi[nt], acc2[mt][nt]);

#pragma unroll
      for (int mt = 0; mt < 2; ++mt)
#pragma unroll
        for (int nt = 0; nt < 4; ++nt)
#pragma unroll
          for (int r = 0; r < 4; ++r)
            us[(mt * 16 + quad * 4 + r) * UP + nt * 16 + lm] =
                f2bf(acc2[mt][nt][r] + b2v[nh][nt]);
#pragma unroll
      for (int s = 0; s < 4; ++s) {
        const int row = s * 8 + (lane >> 3);
        if (i0 + row < Nn) {
          const sh8 v = *(const sh8*)&us[row * UP + (lane & 7) * 8];
          *(sh8*)(hb + (long)(i0 + row) * DN + nh * 64 + (lane & 7) * 8) = v;
        }
      }
    }
  }
}

// ---------------------------------------------------------------------------
// Readout: segmented reduction over sorted batch, then MLP.
// ---------------------------------------------------------------------------
constexpr int GB = 512;

__global__ __launch_bounds__(128) void graph_acc(const unsigned short* __restrict__ hb,
                                                 const int* __restrict__ batch,
                                                 float* __restrict__ gacc,
                                                 float* __restrict__ gcnt) {
  const int c = threadIdx.x;
  const int per = (Nn + GB - 1) / GB;  // 98
  const int s0 = blockIdx.x * per;
  const int s1 = min(s0 + per, Nn);
  if (s0 >= s1) return;
  int cur = batch[s0];
  float acc = 0.f, cnt = 0.f;
  for (int i = s0; i < s1; ++i) {
    const int b = batch[i];
    if (b != cur) {
      atomicAdd(&gacc[cur * DN + c], acc);
      if (c == 0) atomicAdd(&gcnt[cur], cnt);
      acc = 0.f; cnt = 0.f; cur = b;
    }
    acc += bf2f(hb[(long)i * DN + c]);
    cnt += 1.f;
  }
  atomicAdd(&gacc[cur * DN + c], acc);
  if (c == 0) atomicAdd(&gcnt[cur], cnt);
}

__global__ __launch_bounds__(128) void readout(const float* __restrict__ gacc,
                                               const float* __restrict__ gcnt,
                                               const float* __restrict__ w1,
                                               const float* __restrict__ b1,
                                               const float* __restrict__ w2,
                                               const float* __restrict__ b2,
                                               float* __restrict__ out) {
  __shared__ float g[DN], t1[DN];
  const int b = blockIdx.x, c = threadIdx.x;
  const float inv = 1.0f / fmaxf(gcnt[b], 1.0f);
  g[c] = gacc[b * DN + c] * inv;
  __syncthreads();
  float acc = b1[c];
  for (int k = 0; k < DN; ++k) acc += g[k] * w1[k * DN + c];
  t1[c] = fmaxf(acc, 0.0f);
  __syncthreads();
  acc = b2[c];
  for (int k = 0; k < DN; ++k) acc += t1[k] * w2[k * DN + c];
  out[b * DN + c] = acc;
}

// ---------------------------------------------------------------------------
// Launch
// ---------------------------------------------------------------------------
extern "C" void kernel_launch(void* const* d_in, const int* in_sizes, int n_in,
                              void* d_out, int out_size, void* d_ws, size_t ws_size,
                              hipStream_t stream) {
  const float* x       = (const float*)d_in[0];
  const float* ea      = (const float*)d_in[1];
  const int*   ei      = (const int*)d_in[2];
  const int*   batch   = (const int*)d_in[3];
  const float* lin_x_w = (const float*)d_in[4];
  const float* lin_x_b = (const float*)d_in[5];
  const float* lin_e_w = (const float*)d_in[6];
  const float* lin_e_b = (const float*)d_in[7];
  const float* msg_w   = (const float*)d_in[8];
  const float* phie_w1 = (const float*)d_in[9];
  const float* phie_b1 = (const float*)d_in[10];
  const float* phie_w2 = (const float*)d_in[11];
  const float* phie_b2 = (const float*)d_in[12];
  const float* phiv_w1 = (const float*)d_in[13];
  const float* phiv_b1 = (const float*)d_in[14];
  const float* phiv_w2 = (const float*)d_in[15];
  const float* phiv_b2 = (const float*)d_in[16];
  const float* ro_w1   = (const float*)d_in[17];
  const float* ro_b1   = (const float*)d_in[18];
  const float* ro_w2   = (const float*)d_in[19];
  const float* ro_b2   = (const float*)d_in[20];

  const int* srcp = ei;
  const int* dstp = ei + Ne;

  // workspace layout
  int*   deg_i  = (int*)d_ws;                    // Nn    (memset 0)
  float* gacc   = (float*)(deg_i + Nn);          // Bg*DN (memset 0)
  float* gcnt   = gacc + Bg * DN;                // Bg    (memset 0)
  float* invdeg = gcnt + Bg;                     // Nn
  int*   row_ptr= (int*)(invdeg + Nn);           // Nn+8
  int*   cursor = row_ptr + Nn + 8;              // Nn
  int*   bsum   = cursor + Nn;                   // 256
  int*   boff   = bsum + 256;                    // 256
  int*   pos    = boff + 256;                    // Ne
  int*   src_s  = pos + Ne;                      // Ne
  int*   dst_s  = src_s + Ne;                    // Ne
  unsigned short* hb   = (unsigned short*)(dst_s + Ne);  // Nn*DN
  unsigned short* eb   = hb + (long)Nn * DN;     // Ne*DE
  unsigned short* Pm   = eb + (long)Ne * DE;     // Nn*128
  unsigned short* wpT  = Pm + (long)Nn * 128;    // L*128*128
  unsigned short* w1eT = wpT + (long)LAY * 128 * 128;
  unsigned short* ew2T = w1eT + (long)LAY * 64 * 64;
  unsigned short* vw1T = ew2T + (long)LAY * 64 * 64;
  unsigned short* vw2T = vw1T + (long)LAY * 64 * 192;
  unsigned short* wxT  = vw2T + (long)LAY * 128 * 64;  // 128*64

  hipMemsetAsync(deg_i, 0, sizeof(int) * Nn + sizeof(float) * (Bg * DN + Bg), stream);

  // CSR build (dst-sorted edge permutation)
  hist<<<(Ne + 255) / 256, 256, 0, stream>>>(dstp, deg_i);
  scan1<<<SB, 256, 0, stream>>>(deg_i, row_ptr, bsum);
  scan2<<<1, 256, 0, stream>>>(bsum, boff);
  scan3<<<SB, 256, 0, stream>>>(row_ptr, boff, deg_i, cursor, invdeg);
  scatter<<<(Ne + 255) / 256, 256, 0, stream>>>(srcp, dstp, cursor, pos, src_s, dst_s);

  prep_we<<<LAY * 64, 64, 0, stream>>>(phie_w1, msg_w, phie_w2, wpT, w1eT, ew2T);
  prep_wv<<<LAY * 128, 64, 0, stream>>>(phiv_w1, phiv_w2, vw1T, vw2T);
  prep_wx<<<DN, 64, 0, stream>>>(lin_x_w, wxT);

  const int tblocks = ((Nn + 31) / 32 + 3) / 4; // 391
  enc_node_mfma<<<tblocks, 256, 0, stream>>>(x, wxT, lin_x_b, hb);
  enc_edge<<<Ne / 64, 256, 0, stream>>>(ea, pos, lin_e_w, lin_e_b, eb);

  const int eblocks = 782;   // 3128 waves -> exactly 2 tiles/wave over 6250
  const int vblocks = 512;   // 2 blocks/CU (62.5 KB LDS), grid-stride

  for (int l = 0; l < LAY; ++l) {
    proj_mfma<<<tblocks, 256, 0, stream>>>(hb, wpT + (long)l * 128 * 128, Pm);
    edge_layer_mfma<<<eblocks, 256, 0, stream>>>(
        Pm, eb, src_s, dst_s,
        w1eT + (long)l * 64 * 64, ew2T + (long)l * 64 * 64,
        phie_b1 + (long)l * HD, phie_b2 + (long)l * DE);
    node_layer_mfma<<<vblocks, 256, 0, stream>>>(
        hb, eb, row_ptr, invdeg,
        vw1T + (long)l * 64 * 192, vw2T + (long)l * 128 * 64,
        phiv_b1 + (long)l * HD, phiv_b2 + (long)l * DN);
  }

  graph_acc<<<GB, 128, 0, stream>>>(hb, batch, gacc, gcnt);
  readout<<<Bg, 128, 0, stream>>>(gacc, gcnt, ro_w1, ro_b1, ro_w2, ro_b2,
                                  (float*)d_out);
}

// Round 13
// 515.458 us; speedup vs baseline: 1.0577x; 1.0577x over previous
//
#include <hip/hip_runtime.h>

// Problem constants
constexpr int Nn  = 50000;
constexpr int Ne  = 200000;
constexpr int Bg  = 64;
constexpr int DN  = 128;
constexpr int DE  = 64;
constexpr int HD  = 64;
constexpr int INN = 64;
constexpr int INE = 16;
constexpr int LAY = 6;
constexpr int SB  = 196;  // scan blocks: 196*256 >= Nn

typedef __attribute__((ext_vector_type(8))) short sh8;  // 8 bf16 = 4 VGPR
typedef __attribute__((ext_vector_type(4))) float f4;   // C/D frag

__device__ inline unsigned short f2bf(float x) {
  union { float f; unsigned u; } v; v.f = x;
  unsigned r = v.u + 0x7FFF + ((v.u >> 16) & 1);  // RNE
  return (unsigned short)(r >> 16);
}
__device__ inline float bf2f(unsigned short u) {
  union { unsigned u; float f; } v; v.u = ((unsigned)u) << 16; return v.f;
}
__device__ inline f4 mfma16(sh8 a, sh8 b, f4 c) {
  return __builtin_amdgcn_mfma_f32_16x16x32_bf16(a, b, c, 0, 0, 0);
}

// ---------------------------------------------------------------------------
// CSR build: histogram -> exclusive scan -> scatter (dst-sorted permutation)
// ---------------------------------------------------------------------------
__global__ void hist(const int* __restrict__ dst, int* __restrict__ deg) {
  const int j = blockIdx.x * blockDim.x + threadIdx.x;
  if (j < Ne) atomicAdd(&deg[dst[j]], 1);
}

__global__ __launch_bounds__(256) void scan1(const int* __restrict__ deg,
                                             int* __restrict__ rp,
                                             int* __restrict__ bsum) {
  __shared__ int s[256];
  const int t = threadIdx.x, i = blockIdx.x * 256 + t;
  const int v = (i < Nn) ? deg[i] : 0;
  s[t] = v; __syncthreads();
  for (int off = 1; off < 256; off <<= 1) {
    const int x = (t >= off) ? s[t - off] : 0;
    __syncthreads();
    s[t] += x;
    __syncthreads();
  }
  if (i < Nn) rp[i] = s[t] - v;  // intra-block exclusive
  if (t == 255) bsum[blockIdx.x] = s[255];
}

__global__ __launch_bounds__(256) void scan2(const int* __restrict__ bsum,
                                             int* __restrict__ boff) {
  __shared__ int s[256];
  const int t = threadIdx.x;
  const int v = (t < SB) ? bsum[t] : 0;
  s[t] = v; __syncthreads();
  for (int off = 1; off < 256; off <<= 1) {
    const int x = (t >= off) ? s[t - off] : 0;
    __syncthreads();
    s[t] += x;
    __syncthreads();
  }
  if (t < SB) boff[t] = s[t] - v;
}

__global__ __launch_bounds__(256) void scan3(int* __restrict__ rp,
                                             const int* __restrict__ boff,
                                             const int* __restrict__ deg,
                                             int* __restrict__ cursor,
                                             float* __restrict__ invdeg) {
  const int i = blockIdx.x * 256 + threadIdx.x;
  if (i < Nn) {
    const int r = rp[i] + boff[i >> 8];
    rp[i] = r;
    cursor[i] = r;
    invdeg[i] = 1.0f / fmaxf((float)deg[i], 1.0f);
  }
  if (i == 0) rp[Nn] = Ne;
}

__global__ void scatter(const int* __restrict__ src, const int* __restrict__ dst,
                        int* __restrict__ cursor, int* __restrict__ pos,
                        int* __restrict__ src_s, int* __restrict__ dst_s) {
  const int j = blockIdx.x * blockDim.x + threadIdx.x;
  if (j < Ne) {
    const int d = dst[j];
    const int p = atomicAdd(&cursor[d], 1);
    pos[j] = p;       // dst-sorted position of original edge j
    src_s[p] = src[j];
    dst_s[p] = d;
  }
}

// ---------------------------------------------------------------------------
// Weight prep.
// wpT[l][n][k] n<64: fused (W1s + mw@W1e) col n; n>=64: W1d col (n-64). K=128.
// w1eT[l][n][k] = W1e[k][n]; ew2T[l][n][k] = W2[k][n].
// ---------------------------------------------------------------------------
__global__ __launch_bounds__(64) void prep_we(const float* __restrict__ ew1,
                                              const float* __restrict__ mw,
                                              const float* __restrict__ ew2,
                                              unsigned short* __restrict__ wpT,
                                              unsigned short* __restrict__ w1eT,
                                              unsigned short* __restrict__ ew2T) {
  const int l = blockIdx.x >> 6, n = blockIdx.x & 63, t = threadIdx.x;
  const float* E1 = ew1 + (long)l * 320 * 64;
  const float* MW = mw + (long)l * 128 * 64;
  const float* E2 = ew2 + (long)l * 64 * 64;
  unsigned short* WP = wpT + (long)l * 128 * 128;
  __shared__ float c[64];
  c[t] = E1[(256 + t) * 64 + n];  // W1e column n
  __syncthreads();
  for (int k = t; k < 128; k += 64) {
    float s = E1[k * 64 + n];
    for (int j = 0; j < 64; ++j) s += MW[k * 64 + j] * c[j];
    WP[n * 128 + k] = f2bf(s);                        // Ps weight col n
    WP[(64 + n) * 128 + k] = f2bf(E1[(128 + k) * 64 + n]);  // Pd weight col n
  }
  w1eT[(long)l * 64 * 64 + n * 64 + t] = f2bf(E1[(256 + t) * 64 + n]);
  ew2T[(long)l * 64 * 64 + n * 64 + t] = f2bf(E2[t * 64 + n]);
}

__global__ __launch_bounds__(64) void prep_wv(const float* __restrict__ vw1,
                                              const float* __restrict__ vw2,
                                              unsigned short* __restrict__ vw1T,
                                              unsigned short* __restrict__ vw2T) {
  const int l = blockIdx.x >> 7, n = blockIdx.x & 127, t = threadIdx.x;
  vw2T[(long)l * 128 * 64 + n * 64 + t] = f2bf(vw2[(long)l * 64 * 128 + t * 128 + n]);
  if (n < 64) {
    for (int k = t; k < 192; k += 64)
      vw1T[(long)l * 64 * 192 + n * 192 + k] = f2bf(vw1[(long)l * 192 * 64 + k * 64 + n]);
  }
}

// wxT[n][k]: lin_x_w [64][128] -> transposed bf16 [128][64]
__global__ __launch_bounds__(64) void prep_wx(const float* __restrict__ w,
                                              unsigned short* __restrict__ wxT) {
  const int n = blockIdx.x, t = threadIdx.x;
  wxT[n * INN + t] = f2bf(w[t * DN + n]);
}

// ---------------------------------------------------------------------------
// Node encoder (MFMA): h = x @ lin_x_w + b. Wave = 32 nodes, K=64, N=128.
// ---------------------------------------------------------------------------
__global__ __launch_bounds__(256) void enc_node_mfma(
    const float* __restrict__ x,
    const unsigned short* __restrict__ wxT,  // [128][64]
    const float* __restrict__ b,
    unsigned short* __restrict__ hb) {
  const int lane = threadIdx.x & 63;
  const int wv   = threadIdx.x >> 6;
  const int quad = lane >> 4;
  const int lm   = lane & 15;
  const int wid  = blockIdx.x * 4 + wv;
  const int ntiles = (Nn + 31) / 32;  // 1563
  if (wid >= ntiles) return;
  const int i0 = wid * 32;

  bool mv[2];
#pragma unroll
  for (int mt = 0; mt < 2; ++mt) mv[mt] = (i0 + mt * 16) < Nn;

  f4 acc[2][8];
#pragma unroll
  for (int mt = 0; mt < 2; ++mt)
#pragma unroll
    for (int nt = 0; nt < 8; ++nt) acc[mt][nt] = f4{0.f, 0.f, 0.f, 0.f};

#pragma unroll
  for (int ks = 0; ks < 2; ++ks) {
    const int kb = ks * 32 + quad * 8;
    sh8 a[2], bfr[8];
#pragma unroll
    for (int mt = 0; mt < 2; ++mt) {
      const int row = i0 + mt * 16 + lm;
      if (mv[mt] && row < Nn) {
        const float* xp = x + (long)row * INN + kb;
        const float4 v0 = *(const float4*)xp;
        const float4 v1 = *(const float4*)(xp + 4);
        a[mt][0] = (short)f2bf(v0.x); a[mt][1] = (short)f2bf(v0.y);
        a[mt][2] = (short)f2bf(v0.z); a[mt][3] = (short)f2bf(v0.w);
        a[mt][4] = (short)f2bf(v1.x); a[mt][5] = (short)f2bf(v1.y);
        a[mt][6] = (short)f2bf(v1.z); a[mt][7] = (short)f2bf(v1.w);
      } else a[mt] = (sh8)0;
    }
#pragma unroll
    for (int nt = 0; nt < 8; ++nt)
      bfr[nt] = *(const sh8*)(wxT + (nt * 16 + lm) * INN + kb);
#pragma unroll
    for (int mt = 0; mt < 2; ++mt)
#pragma unroll
      for (int nt = 0; nt < 8; ++nt)
        acc[mt][nt] = mfma16(a[mt], bfr[nt], acc[mt][nt]);
  }
  float bv[8];
#pragma unroll
  for (int nt = 0; nt < 8; ++nt) bv[nt] = b[nt * 16 + lm];
#pragma unroll
  for (int mt = 0; mt < 2; ++mt) {
    if (!mv[mt]) continue;
#pragma unroll
    for (int r = 0; r < 4; ++r) {
      const int row = i0 + mt * 16 + quad * 4 + r;
      if (row >= Nn) continue;
#pragma unroll
      for (int nt = 0; nt < 8; ++nt)
        hb[(long)row * DN + nt * 16 + lm] = f2bf(acc[mt][nt][r] + bv[nt]);
    }
  }
}

// ---------------------------------------------------------------------------
// Edge encoder: sequential coalesced read of ea, scatter-write to dst-sorted eb.
// ---------------------------------------------------------------------------
__global__ __launch_bounds__(256) void enc_edge(const float* __restrict__ ea,
                                                const int* __restrict__ pos,
                                                const float* __restrict__ w,
                                                const float* __restrict__ b,
                                                unsigned short* __restrict__ eb) {
  __shared__ float S[64 * INE];
  const int t = threadIdx.x;
  const int j0 = blockIdx.x * 64;  // Ne/64 = 3125 blocks
  *(float4*)&S[t * 4] = *(const float4*)&ea[(long)j0 * INE + t * 4];
  __syncthreads();
  const int lane = t & 63, wv = t >> 6;
  float wreg[INE];
#pragma unroll
  for (int k = 0; k < INE; ++k) wreg[k] = w[k * DE + lane];
  const float bias = b[lane];
#pragma unroll
  for (int el = 0; el < 16; ++el) {
    const int e = wv * 16 + el;
    float acc = bias;
#pragma unroll
    for (int k = 0; k < INE; ++k) acc += S[e * INE + k] * wreg[k];
    eb[(long)pos[j0 + e] * DE + lane] = f2bf(acc);
  }
}

// ---------------------------------------------------------------------------
// Per-node projection: P = hb @ [W1s' | W1d]  (Nn x 128, bf16).
// Wave = 32 rows, K=128, N=128. Streaming; staged coalesced stores.
// ---------------------------------------------------------------------------
constexpr int PP = 136;  // P-staging pitch (272B rows)

__global__ __launch_bounds__(256) void proj_mfma(
    const unsigned short* __restrict__ hb,
    const unsigned short* __restrict__ wpT,  // [128][128]
    unsigned short* __restrict__ P) {
  __shared__ unsigned short Us[4][32 * PP];
  const int lane = threadIdx.x & 63;
  const int wv   = threadIdx.x >> 6;
  const int quad = lane >> 4;
  const int lm   = lane & 15;
  const int kq   = quad * 8;
  const int wid  = blockIdx.x * 4 + wv;
  const int ntiles = (Nn + 31) / 32;  // 1563
  if (wid >= ntiles) return;
  const int i0 = wid * 32;
  unsigned short* us = Us[wv];

  bool mv[2];
#pragma unroll
  for (int mt = 0; mt < 2; ++mt) mv[mt] = (i0 + mt * 16) < Nn;

  sh8 a[2][4];
#pragma unroll
  for (int mt = 0; mt < 2; ++mt) {
    const int row = i0 + mt * 16 + lm;
    if (mv[mt]) {
#pragma unroll
      for (int ks = 0; ks < 4; ++ks)
        a[mt][ks] = *(const sh8*)(hb + (long)row * DN + ks * 32 + kq);
    } else {
#pragma unroll
      for (int ks = 0; ks < 4; ++ks) a[mt][ks] = (sh8)0;
    }
  }

  f4 acc[2][8];
#pragma unroll
  for (int mt = 0; mt < 2; ++mt)
#pragma unroll
    for (int nt = 0; nt < 8; ++nt) acc[mt][nt] = f4{0.f, 0.f, 0.f, 0.f};

#pragma unroll
  for (int ks = 0; ks < 4; ++ks) {
    const int kb = ks * 32 + kq;
    sh8 bfr[8];
#pragma unroll
    for (int nt = 0; nt < 8; ++nt)
      bfr[nt] = *(const sh8*)(wpT + (nt * 16 + lm) * 128 + kb);
#pragma unroll
    for (int mt = 0; mt < 2; ++mt)
#pragma unroll
      for (int nt = 0; nt < 8; ++nt)
        acc[mt][nt] = mfma16(a[mt][ks], bfr[nt], acc[mt][nt]);
  }

#pragma unroll
  for (int mt = 0; mt < 2; ++mt)
#pragma unroll
    for (int nt = 0; nt < 8; ++nt)
#pragma unroll
      for (int r = 0; r < 4; ++r)
        us[(mt * 16 + quad * 4 + r) * PP + nt * 16 + lm] = f2bf(acc[mt][nt][r]);
#pragma unroll
  for (int s = 0; s < 8; ++s) {
    const int row = s * 4 + (lane >> 4);
    const int col8 = (lane & 15) * 8;
    if (i0 + row < Nn) {
      const sh8 v = *(const sh8*)&us[row * PP + col8];
      *(sh8*)(P + (long)(i0 + row) * 128 + col8) = v;
    }
  }
}

// ---------------------------------------------------------------------------
// Edge layer (MFMA). u = relu(Ps[src] + Pd[dst] + e@W1e + b1) via identity
// MFMAs; e' = [u|e]@[W2;I] + b2. Weights in LDS; grid-stride; staged stores.
// Grid = 1024 blocks: fills the 4-blocks/CU LDS capacity exactly (R12 lesson:
// under-filling residency costs more than tail imbalance).
// ---------------------------------------------------------------------------
constexpr int UP = 72;   // Us / weight LDS pitch (144B rows)

__global__ __launch_bounds__(256) void edge_layer_mfma(
    const unsigned short* __restrict__ P,
    unsigned short* __restrict__ eb,
    const int* __restrict__ src_s, const int* __restrict__ dst_s,
    const unsigned short* __restrict__ w1eT,  // [64][64]
    const unsigned short* __restrict__ ew2T,  // [64][64]
    const float* __restrict__ b1, const float* __restrict__ b2) {
  __shared__ unsigned short W1l[64 * UP];   // 9216 B
  __shared__ unsigned short W2l[64 * UP];   // 9216 B
  __shared__ unsigned short Us[4][32 * UP]; // 18432 B (total 36864 B -> 4 blocks/CU)
  const int t    = threadIdx.x;
  const int lane = t & 63;
  const int wv   = t >> 6;
  const int quad = lane >> 4;
  const int lm   = lane & 15;
  const int kq   = quad * 8;
  unsigned short* us = Us[wv];

#pragma unroll
  for (int c = 0; c < 2; ++c) {
    const int cc = c * 256 + t;
    const int n = cc >> 3, kc = (cc & 7) * 8;
    *(sh8*)&W1l[n * UP + kc] = *(const sh8*)(w1eT + n * 64 + kc);
    *(sh8*)&W2l[n * UP + kc] = *(const sh8*)(ew2T + n * 64 + kc);
  }
  __syncthreads();

  float b1v[4], b2v[4];
  sh8 bi[4];
#pragma unroll
  for (int nt = 0; nt < 4; ++nt) {
    b1v[nt] = b1[nt * 16 + lm];
    b2v[nt] = b2[nt * 16 + lm];
    const int d = nt * 16 + lm - (nt >> 1) * 32 - kq;
#pragma unroll
    for (int jj = 0; jj < 8; ++jj) bi[nt][jj] = (d == jj) ? (short)0x3F80 : (short)0;
  }

  const int ntiles = Ne / 32;  // 6250
  const int nw = gridDim.x * 4;
  for (int wid = blockIdx.x * 4 + wv; wid < ntiles; wid += nw) {
    const int j0 = wid * 32;

    sh8 as_[2][2], ad_[2][2], ae_[2][2];
#pragma unroll
    for (int mt = 0; mt < 2; ++mt) {
      const int j = j0 + mt * 16 + lm;
      const long srow = (long)src_s[j] * 128;
      const long drow = (long)dst_s[j] * 128 + 64;
#pragma unroll
      for (int ks = 0; ks < 2; ++ks) {
        as_[mt][ks] = *(const sh8*)(P + srow + ks * 32 + kq);
        ad_[mt][ks] = *(const sh8*)(P + drow + ks * 32 + kq);
        ae_[mt][ks] = *(const sh8*)(eb + (long)j * DE + ks * 32 + kq);
      }
    }

    f4 acc[2][4];
#pragma unroll
    for (int mt = 0; mt < 2; ++mt)
#pragma unroll
      for (int nt = 0; nt < 4; ++nt) acc[mt][nt] = f4{0.f, 0.f, 0.f, 0.f};
#pragma unroll
    for (int ks = 0; ks < 2; ++ks) {
      const int kb = ks * 32 + kq;
      sh8 b[4];
#pragma unroll
      for (int nt = 0; nt < 4; ++nt)
        b[nt] = *(const sh8*)&W1l[(nt * 16 + lm) * UP + kb];
#pragma unroll
      for (int mt = 0; mt < 2; ++mt)
#pragma unroll
        for (int nt = 0; nt < 4; ++nt)
          acc[mt][nt] = mfma16(ae_[mt][ks], b[nt], acc[mt][nt]);
    }
#pragma unroll
    for (int nt = 0; nt < 4; ++nt)
#pragma unroll
      for (int mt = 0; mt < 2; ++mt) {
        acc[mt][nt] = mfma16(as_[mt][nt >> 1], bi[nt], acc[mt][nt]);
        acc[mt][nt] = mfma16(ad_[mt][nt >> 1], bi[nt], acc[mt][nt]);
      }

#pragma unroll
    for (int mt = 0; mt < 2; ++mt)
#pragma unroll
      for (int nt = 0; nt < 4; ++nt)
#pragma unroll
        for (int r = 0; r < 4; ++r) {
          const int row = mt * 16 + quad * 4 + r;
          const int col = nt * 16 + lm;
          us[row * UP + col] = f2bf(fmaxf(acc[mt][nt][r] + b1v[nt], 0.f));
        }

    f4 acc2[2][4];
#pragma unroll
    for (int mt = 0; mt < 2; ++mt)
#pragma unroll
      for (int nt = 0; nt < 4; ++nt) acc2[mt][nt] = f4{0.f, 0.f, 0.f, 0.f};
#pragma unroll
    for (int ks = 0; ks < 2; ++ks) {
      const int kb = ks * 32 + kq;
      sh8 au[2], b[4];
#pragma unroll
      for (int mt = 0; mt < 2; ++mt)
        au[mt] = *(const sh8*)&us[(mt * 16 + lm) * UP + kb];
#pragma unroll
      for (int nt = 0; nt < 4; ++nt)
        b[nt] = *(const sh8*)&W2l[(nt * 16 + lm) * UP + kb];
#pragma unroll
      for (int mt = 0; mt < 2; ++mt)
#pragma unroll
        for (int nt = 0; nt < 4; ++nt)
          acc2[mt][nt] = mfma16(au[mt], b[nt], acc2[mt][nt]);
    }
#pragma unroll
    for (int nt = 0; nt < 4; ++nt)
#pragma unroll
      for (int mt = 0; mt < 2; ++mt)
        acc2[mt][nt] = mfma16(ae_[mt][nt >> 1], bi[nt], acc2[mt][nt]);

#pragma unroll
    for (int mt = 0; mt < 2; ++mt)
#pragma unroll
      for (int nt = 0; nt < 4; ++nt)
#pragma unroll
        for (int r = 0; r < 4; ++r)
          us[(mt * 16 + quad * 4 + r) * UP + nt * 16 + lm] =
              f2bf(acc2[mt][nt][r] + b2v[nt]);
#pragma unroll
    for (int s = 0; s < 4; ++s) {
      const int row = s * 8 + (lane >> 3);
      const sh8 v = *(const sh8*)&us[row * UP + (lane & 7) * 8];
      *(sh8*)(eb + (long)(j0 + row) * DE + (lane & 7) * 8) = v;
    }
  }
}

// ---------------------------------------------------------------------------
// Node layer (MFMA) with FUSED csr-mean (R9/R10 version).
// ---------------------------------------------------------------------------
constexpr int VP1 = 200;              // vw1T LDS pitch (400B rows)
constexpr int VP2 = 72;               // vw2T LDS pitch (144B rows)
constexpr int V2OFF = 64 * VP1;       // vw2T offset in Wl

__global__ __launch_bounds__(256) void node_layer_mfma(
    unsigned short* __restrict__ hb,
    const unsigned short* __restrict__ eb,
    const int* __restrict__ rp,
    const float* __restrict__ invdeg,
    const unsigned short* __restrict__ vw1T,  // [64][192]
    const unsigned short* __restrict__ vw2T,  // [128][64]
    const float* __restrict__ b1, const float* __restrict__ b2) {
  __shared__ unsigned short Wl[64 * VP1 + 128 * VP2];  // 44032 B
  __shared__ unsigned short Us[4][32 * UP];            // 18432 B (total 62464 B)
  const int t    = threadIdx.x;
  const int lane = t & 63;
  const int wv   = t >> 6;
  const int quad = lane >> 4;
  const int lm   = lane & 15;
  const int kq   = quad * 8;
  unsigned short* us = Us[wv];

#pragma unroll
  for (int c = 0; c < 6; ++c) {
    const int cc = c * 256 + t;
    const int n = cc / 24, kc = (cc % 24) * 8;
    *(sh8*)&Wl[n * VP1 + kc] = *(const sh8*)(vw1T + n * 192 + kc);
  }
#pragma unroll
  for (int c = 0; c < 4; ++c) {
    const int cc = c * 256 + t;
    const int n = cc / 8, kc = (cc % 8) * 8;
    *(sh8*)&Wl[V2OFF + n * VP2 + kc] = *(const sh8*)(vw2T + n * 64 + kc);
  }
  __syncthreads();

  float b1v[4];
  sh8 bi[4];
#pragma unroll
  for (int nt = 0; nt < 4; ++nt) {
    b1v[nt] = b1[nt * 16 + lm];
    const int d = nt * 16 + lm - (nt >> 1) * 32 - kq;
#pragma unroll
    for (int jj = 0; jj < 8; ++jj) bi[nt][jj] = (d == jj) ? (short)0x3F80 : (short)0;
  }
  float b2v[2][4];
#pragma unroll
  for (int nh = 0; nh < 2; ++nh)
#pragma unroll
    for (int nt = 0; nt < 4; ++nt) b2v[nh][nt] = b2[nh * 64 + nt * 16 + lm];

  const int ntiles = (Nn + 31) / 32;  // 1563
  const int nw = gridDim.x * 4;
  for (int wid = blockIdx.x * 4 + wv; wid < ntiles; wid += nw) {
    const int i0 = wid * 32;
    bool mv[2];
#pragma unroll
    for (int mt = 0; mt < 2; ++mt) mv[mt] = (i0 + mt * 16) < Nn;

    sh8 a[2][6];
#pragma unroll
    for (int mt = 0; mt < 2; ++mt) {
      const int row = i0 + mt * 16 + lm;
      if (mv[mt]) {
#pragma unroll
        for (int ks = 0; ks < 4; ++ks)
          a[mt][ks] = *(const sh8*)(hb + (long)row * DN + ks * 32 + kq);
        const int js = rp[row], je = rp[row + 1];
        float m0[8], m1[8];
#pragma unroll
        for (int c = 0; c < 8; ++c) { m0[c] = 0.f; m1[c] = 0.f; }
        for (int j = js; j < je; ++j) {
          const sh8 v0 = *(const sh8*)(eb + (long)j * DE + kq);
          const sh8 v1 = *(const sh8*)(eb + (long)j * DE + 32 + kq);
#pragma unroll
          for (int c = 0; c < 8; ++c) {
            m0[c] += bf2f((unsigned short)v0[c]);
            m1[c] += bf2f((unsigned short)v1[c]);
          }
        }
        const float inv = invdeg[row];
        sh8 f0, f1;
#pragma unroll
        for (int c = 0; c < 8; ++c) {
          f0[c] = (short)f2bf(m0[c] * inv);
          f1[c] = (short)f2bf(m1[c] * inv);
        }
        a[mt][4] = f0;
        a[mt][5] = f1;
      } else {
#pragma unroll
        for (int ks = 0; ks < 6; ++ks) a[mt][ks] = (sh8)0;
      }
    }

    f4 acc[2][4];
#pragma unroll
    for (int mt = 0; mt < 2; ++mt)
#pragma unroll
      for (int nt = 0; nt < 4; ++nt) acc[mt][nt] = f4{0.f, 0.f, 0.f, 0.f};
#pragma unroll
    for (int ks = 0; ks < 6; ++ks) {
      const int kb = ks * 32 + kq;
      sh8 b[4];
#pragma unroll
      for (int nt = 0; nt < 4; ++nt)
        b[nt] = *(const sh8*)&Wl[(nt * 16 + lm) * VP1 + kb];
#pragma unroll
      for (int mt = 0; mt < 2; ++mt)
#pragma unroll
        for (int nt = 0; nt < 4; ++nt)
          acc[mt][nt] = mfma16(a[mt][ks], b[nt], acc[mt][nt]);
    }
#pragma unroll
    for (int mt = 0; mt < 2; ++mt)
#pragma unroll
      for (int nt = 0; nt < 4; ++nt)
#pragma unroll
        for (int r = 0; r < 4; ++r) {
          const int row = mt * 16 + quad * 4 + r;
          const int col = nt * 16 + lm;
          us[row * UP + col] = f2bf(fmaxf(acc[mt][nt][r] + b1v[nt], 0.f));
        }

    sh8 au[2][2];
#pragma unroll
    for (int ks = 0; ks < 2; ++ks)
#pragma unroll
      for (int mt = 0; mt < 2; ++mt)
        au[mt][ks] = *(const sh8*)&us[(mt * 16 + lm) * UP + ks * 32 + kq];

#pragma unroll
    for (int nh = 0; nh < 2; ++nh) {
      f4 acc2[2][4];
#pragma unroll
      for (int mt = 0; mt < 2; ++mt)
#pragma unroll
        for (int nt = 0; nt < 4; ++nt) acc2[mt][nt] = f4{0.f, 0.f, 0.f, 0.f};
#pragma unroll
      for (int ks = 0; ks < 2; ++ks) {
        const int kb = ks * 32 + kq;
        sh8 b[4];
#pragma unroll
        for (int nt = 0; nt < 4; ++nt)
          b[nt] = *(const sh8*)&Wl[V2OFF + (nh * 64 + nt * 16 + lm) * VP2 + kb];
#pragma unroll
        for (int mt = 0; mt < 2; ++mt)
#pragma unroll
          for (int nt = 0; nt < 4; ++nt)
            acc2[mt][nt] = mfma16(au[mt][ks], b[nt], acc2[mt][nt]);
      }
#pragma unroll
      for (int nt = 0; nt < 4; ++nt)
#pragma unroll
        for (int mt = 0; mt < 2; ++mt)
          acc2[mt][nt] = mfma16(a[mt][nh * 2 + (nt >> 1)], bi[nt], acc2[mt][nt]);

#pragma unroll
      for (int mt = 0; mt < 2; ++mt)
#pragma unroll
        for (int nt = 0; nt < 4; ++nt)
#pragma unroll
          for (int r = 0; r < 4; ++r)
            us[(mt * 16 + quad * 4 + r) * UP + nt * 16 + lm] =
                f2bf(acc2[mt][nt][r] + b2v[nh][nt]);
#pragma unroll
      for (int s = 0; s < 4; ++s) {
        const int row = s * 8 + (lane >> 3);
        if (i0 + row < Nn) {
          const sh8 v = *(const sh8*)&us[row * UP + (lane & 7) * 8];
          *(sh8*)(hb + (long)(i0 + row) * DN + nh * 64 + (lane & 7) * 8) = v;
        }
      }
    }
  }
}

// ---------------------------------------------------------------------------
// Readout: segmented reduction over sorted batch, then MLP.
// ---------------------------------------------------------------------------
constexpr int GB = 512;

__global__ __launch_bounds__(128) void graph_acc(const unsigned short* __restrict__ hb,
                                                 const int* __restrict__ batch,
                                                 float* __restrict__ gacc,
                                                 float* __restrict__ gcnt) {
  const int c = threadIdx.x;
  const int per = (Nn + GB - 1) / GB;  // 98
  const int s0 = blockIdx.x * per;
  const int s1 = min(s0 + per, Nn);
  if (s0 >= s1) return;
  int cur = batch[s0];
  float acc = 0.f, cnt = 0.f;
  for (int i = s0; i < s1; ++i) {
    const int b = batch[i];
    if (b != cur) {
      atomicAdd(&gacc[cur * DN + c], acc);
      if (c == 0) atomicAdd(&gcnt[cur], cnt);
      acc = 0.f; cnt = 0.f; cur = b;
    }
    acc += bf2f(hb[(long)i * DN + c]);
    cnt += 1.f;
  }
  atomicAdd(&gacc[cur * DN + c], acc);
  if (c == 0) atomicAdd(&gcnt[cur], cnt);
}

__global__ __launch_bounds__(128) void readout(const float* __restrict__ gacc,
                                               const float* __restrict__ gcnt,
                                               const float* __restrict__ w1,
                                               const float* __restrict__ b1,
                                               const float* __restrict__ w2,
                                               const float* __restrict__ b2,
                                               float* __restrict__ out) {
  __shared__ float g[DN], t1[DN];
  const int b = blockIdx.x, c = threadIdx.x;
  const float inv = 1.0f / fmaxf(gcnt[b], 1.0f);
  g[c] = gacc[b * DN + c] * inv;
  __syncthreads();
  float acc = b1[c];
  for (int k = 0; k < DN; ++k) acc += g[k] * w1[k * DN + c];
  t1[c] = fmaxf(acc, 0.0f);
  __syncthreads();
  acc = b2[c];
  for (int k = 0; k < DN; ++k) acc += t1[k] * w2[k * DN + c];
  out[b * DN + c] = acc;
}

// ---------------------------------------------------------------------------
// Launch
// ---------------------------------------------------------------------------
extern "C" void kernel_launch(void* const* d_in, const int* in_sizes, int n_in,
                              void* d_out, int out_size, void* d_ws, size_t ws_size,
                              hipStream_t stream) {
  const float* x       = (const float*)d_in[0];
  const float* ea      = (const float*)d_in[1];
  const int*   ei      = (const int*)d_in[2];
  const int*   batch   = (const int*)d_in[3];
  const float* lin_x_w = (const float*)d_in[4];
  const float* lin_x_b = (const float*)d_in[5];
  const float* lin_e_w = (const float*)d_in[6];
  const float* lin_e_b = (const float*)d_in[7];
  const float* msg_w   = (const float*)d_in[8];
  const float* phie_w1 = (const float*)d_in[9];
  const float* phie_b1 = (const float*)d_in[10];
  const float* phie_w2 = (const float*)d_in[11];
  const float* phie_b2 = (const float*)d_in[12];
  const float* phiv_w1 = (const float*)d_in[13];
  const float* phiv_b1 = (const float*)d_in[14];
  const float* phiv_w2 = (const float*)d_in[15];
  const float* phiv_b2 = (const float*)d_in[16];
  const float* ro_w1   = (const float*)d_in[17];
  const float* ro_b1   = (const float*)d_in[18];
  const float* ro_w2   = (const float*)d_in[19];
  const float* ro_b2   = (const float*)d_in[20];

  const int* srcp = ei;
  const int* dstp = ei + Ne;

  // workspace layout
  int*   deg_i  = (int*)d_ws;                    // Nn    (memset 0)
  float* gacc   = (float*)(deg_i + Nn);          // Bg*DN (memset 0)
  float* gcnt   = gacc + Bg * DN;                // Bg    (memset 0)
  float* invdeg = gcnt + Bg;                     // Nn
  int*   row_ptr= (int*)(invdeg + Nn);           // Nn+8
  int*   cursor = row_ptr + Nn + 8;              // Nn
  int*   bsum   = cursor + Nn;                   // 256
  int*   boff   = bsum + 256;                    // 256
  int*   pos    = boff + 256;                    // Ne
  int*   src_s  = pos + Ne;                      // Ne
  int*   dst_s  = src_s + Ne;                    // Ne
  unsigned short* hb   = (unsigned short*)(dst_s + Ne);  // Nn*DN
  unsigned short* eb   = hb + (long)Nn * DN;     // Ne*DE
  unsigned short* Pm   = eb + (long)Ne * DE;     // Nn*128
  unsigned short* wpT  = Pm + (long)Nn * 128;    // L*128*128
  unsigned short* w1eT = wpT + (long)LAY * 128 * 128;
  unsigned short* ew2T = w1eT + (long)LAY * 64 * 64;
  unsigned short* vw1T = ew2T + (long)LAY * 64 * 64;
  unsigned short* vw2T = vw1T + (long)LAY * 64 * 192;
  unsigned short* wxT  = vw2T + (long)LAY * 128 * 64;  // 128*64

  hipMemsetAsync(deg_i, 0, sizeof(int) * Nn + sizeof(float) * (Bg * DN + Bg), stream);

  // CSR build (dst-sorted edge permutation)
  hist<<<(Ne + 255) / 256, 256, 0, stream>>>(dstp, deg_i);
  scan1<<<SB, 256, 0, stream>>>(deg_i, row_ptr, bsum);
  scan2<<<1, 256, 0, stream>>>(bsum, boff);
  scan3<<<SB, 256, 0, stream>>>(row_ptr, boff, deg_i, cursor, invdeg);
  scatter<<<(Ne + 255) / 256, 256, 0, stream>>>(srcp, dstp, cursor, pos, src_s, dst_s);

  prep_we<<<LAY * 64, 64, 0, stream>>>(phie_w1, msg_w, phie_w2, wpT, w1eT, ew2T);
  prep_wv<<<LAY * 128, 64, 0, stream>>>(phiv_w1, phiv_w2, vw1T, vw2T);
  prep_wx<<<DN, 64, 0, stream>>>(lin_x_w, wxT);

  const int tblocks = ((Nn + 31) / 32 + 3) / 4; // 391
  enc_node_mfma<<<tblocks, 256, 0, stream>>>(x, wxT, lin_x_b, hb);
  enc_edge<<<Ne / 64, 256, 0, stream>>>(ea, pos, lin_e_w, lin_e_b, eb);

  const int eblocks = 1024;  // 4 blocks/CU capacity (36.9 KB LDS), grid-stride
  const int vblocks = 512;   // 2 blocks/CU capacity (62.5 KB LDS), grid-stride

  for (int l = 0; l < LAY; ++l) {
    proj_mfma<<<tblocks, 256, 0, stream>>>(hb, wpT + (long)l * 128 * 128, Pm);
    edge_layer_mfma<<<eblocks, 256, 0, stream>>>(
        Pm, eb, src_s, dst_s,
        w1eT + (long)l * 64 * 64, ew2T + (long)l * 64 * 64,
        phie_b1 + (long)l * HD, phie_b2 + (long)l * DE);
    node_layer_mfma<<<vblocks, 256, 0, stream>>>(
        hb, eb, row_ptr, invdeg,
        vw1T + (long)l * 64 * 192, vw2T + (long)l * 128 * 64,
        phiv_b1 + (long)l * HD, phiv_b2 + (long)l * DN);
  }

  graph_acc<<<GB, 128, 0, stream>>>(hb, batch, gacc, gcnt);
  readout<<<Bg, 128, 0, stream>>>(gacc, gcnt, ro_w1, ro_b1, ro_w2, ro_b2,
                                  (float*)d_out);
}